// Round 13
// baseline (580.625 us; speedup 1.0000x reference)
//
#include <hip/hip_runtime.h>
#include <cstdint>

typedef _Float16 half2_t __attribute__((ext_vector_type(2)));

#define B_   128
#define T_   2048
#define E_   8
#define OUT_ 32
#define HID_ 64
#define KC_  8
#define TILE_A 128
#define NSEG 2
#define SPLIT 1088           // seg0 outputs [0,1088), seg1 outputs [1088,2048)
#define WUPC 2               // seg1 warmup chunks (2 x 64 = 128 steps)
#define CH_  64              // chunk length (R7-proven)
#define NCHB 17              // chunks per block (1088 steps, both segments)

__device__ __forceinline__ float frcp(float x) { return __builtin_amdgcn_rcpf(x); }
__device__ __forceinline__ float exp2_(float x) {
#if __has_builtin(__builtin_amdgcn_exp2f)
  return __builtin_amdgcn_exp2f(x);
#else
  return exp2f(x);
#endif
}
__device__ __forceinline__ float fsig(float x) { return frcp(1.0f + __expf(-x)); }

__device__ __forceinline__ float fdot2_(half2_t a, half2_t b, float c) {
#if __has_builtin(__builtin_amdgcn_fdot2)
  return __builtin_amdgcn_fdot2(a, b, c, false);
#else
  return fmaf((float)a.x, (float)b.x, fmaf((float)a.y, (float)b.y, c));
#endif
}

__device__ __forceinline__ half2_t u2h2(unsigned u) {
  return __builtin_bit_cast(half2_t, u);
}
__device__ __forceinline__ half2_t packh2(float a, float b) {
  half2_t h; h.x = (_Float16)a; h.y = (_Float16)b; return h;
}

#define NLOG2E  (-1.4426950408889634f)
#define N2LOG2E (-2.8853900817779268f)

// Per-(b,t) scalar KAN pieces. All b-spline denominators fold to compile-time constants.
__device__ __forceinline__ void kan_scalars(float x, const float* gwr, const float* gbr,
                                            float& silu, float* gate, float* bs) {
  silu = x * fsig(x);
  float le[E_];
  float m = -1e30f;
#pragma unroll
  for (int e = 0; e < E_; ++e) { le[e] = fmaf(x, gwr[e], gbr[e]); m = fmaxf(m, le[e]); }
  float s = 0.f;
#pragma unroll
  for (int e = 0; e < E_; ++e) { gate[e] = __expf(le[e] - m); s += gate[e]; }
  float inv = frcp(s);
#pragma unroll
  for (int e = 0; e < E_; ++e) gate[e] *= inv;
  float g[12];
#pragma unroll
  for (int i = 0; i < 12; ++i) g[i] = (float)(i - 3) * 0.4f - 1.0f;
  float bb[11];
#pragma unroll
  for (int i = 0; i < 11; ++i) bb[i] = (x >= g[i] && x < g[i + 1]) ? 1.0f : 0.0f;
#pragma unroll
  for (int k = 1; k <= 3; ++k) {
#pragma unroll
    for (int i = 0; i < 11 - k; ++i) {
      const float dl = 1.0f / (g[i + k] - g[i]);
      const float dr = 1.0f / (g[i + k + 1] - g[i + 1]);
      float left  = (x - g[i]) * dl;
      float right = (g[i + k + 1] - x) * dr;
      bb[i] = left * bb[i] + right * bb[i + 1];
    }
  }
#pragma unroll
  for (int i = 0; i < KC_; ++i) bs[i] = bb[i];
}

// ---------------- 256 blocks == 1 GRU block/CU (fast regime), NSEG=2, conv tail.
// GRU engine is the EXACT R7 structure (CH=64, LDS packsw producer pack, split
// xqrz/xqn, consumer read order h-write -> xq-prefetch -> u-prefetch), which
// measured 832 cyc/step; R8-R12's CH=32 + readlane engine measured 1257 at the
// same residency. Segments: seg0 t[0,1088) no warmup; seg1 from t=960 with 2
// warmup chunks (seam error ~0.9^128 ~ 4e-7). Conv runs as an 8-tile tail.
__global__ __launch_bounds__(256, 1) void fused5_kernel(
    const float* __restrict__ a, const float* __restrict__ d,
    const float* __restrict__ gwa, const float* __restrict__ gba,
    const float* __restrict__ bwa, const float* __restrict__ swa,
    const float* __restrict__ gwd, const float* __restrict__ gbd,
    const float* __restrict__ bwd, const float* __restrict__ swd,
    const float* __restrict__ cw, const float* __restrict__ cb,
    const float* __restrict__ wih_g, const float* __restrict__ whh_g,
    const float* __restrict__ bih_g, const float* __restrict__ bhh_g,
    float* __restrict__ out)
{
  __shared__ __align__(16) char smem_[61568];
  const int tid = threadIdx.x;

  // ======================= GRU phase =======================
  auto xqrz   = (unsigned (*)[CH_][64])smem_;                       // 32768 B
  auto xqn    = (_Float16 (*)[CH_][64])(smem_ + 32768);             // 16384 B
  auto packsw = (float (*)[CH_][16])(smem_ + 49152);                // 12288 B
  auto hbc    = (unsigned short*)(smem_ + 61440);                   //   128 B

  const int bid = (int)blockIdx.x;
  const int b = bid & (B_ - 1);
  const int seg = bid >> 7;
  const int tstart = (seg == 0) ? 0 : (SPLIT - WUPC * CH_);   // 0 or 960
  const int wup = (seg == 0) ? 0 : WUPC;
  const int w = tid >> 6;
  const int ln = tid & 63;
  const size_t db = (size_t)b * T_;
  float* outrow = out + db * 96 + 32;
  const uint4* hq4 = (const uint4*)hbc;

  // ---- wave 0: w_hh as f16 pairs, pre-scaled (lane ln owns rows ln, 64+ln, 128+ln)
  half2_t whhp[3][32];
  float bhh3[3];
  uint4 u0, u1, u2, u3, u4, u5, u6, u7;   // persistent h-broadcast regs (wave 0)
  if (w == 0) {
#pragma unroll
    for (int g3 = 0; g3 < 3; ++g3) {
      const float sc = (g3 == 2) ? N2LOG2E : NLOG2E;
      const int g = g3 * 64 + ln;
#pragma unroll
      for (int i = 0; i < 64; i += 4) {
        const float4 v = *(const float4*)&whh_g[(size_t)g * 64 + i];
        whhp[g3][i / 2]     = packh2(v.x * sc, v.y * sc);
        whhp[g3][i / 2 + 1] = packh2(v.z * sc, v.w * sc);
      }
      bhh3[g3] = bhh_g[g] * sc;
    }
    hbc[ln] = __builtin_bit_cast(unsigned short, (_Float16)0.0f);
    asm volatile("" ::: "memory");
    u0 = hq4[0]; u1 = hq4[1]; u2 = hq4[2]; u3 = hq4[3];
    u4 = hq4[4]; u5 = hq4[5]; u6 = hq4[6]; u7 = hq4[7];
  }

  // ---- waves 1-3: folded weights for gate g = (w-1)*64 + ln (pre-scaled)
  float A_[E_];
  half2_t Beh[E_][4];
  float bihr = 0.f;
  float gwrd[E_], gbrd[E_];
  const int p3 = (w >= 1) ? (w - 1) : 0;
  if (w >= 1) {
    const float sc = (p3 == 2) ? N2LOG2E : NLOG2E;
    const int g = p3 * 64 + ln;
    float wihr[32];
#pragma unroll
    for (int i = 0; i < 32; i += 4) {
      float4 v = *(const float4*)&wih_g[(size_t)g * 32 + i];
      wihr[i] = v.x * sc; wihr[i + 1] = v.y * sc;
      wihr[i + 2] = v.z * sc; wihr[i + 3] = v.w * sc;
    }
    bihr = bih_g[g] * sc;
#pragma unroll
    for (int e = 0; e < E_; ++e) { gwrd[e] = gwd[e]; gbrd[e] = gbd[e]; }
#pragma unroll
    for (int e = 0; e < E_; ++e) {
      float acc = 0.f;
#pragma unroll 4
      for (int c = 0; c < 32; c += 4) {
        const float4 bv = *(const float4*)&bwd[e * OUT_ + c];
        acc = fmaf(wihr[c], bv.x, acc);
        acc = fmaf(wihr[c + 1], bv.y, acc);
        acc = fmaf(wihr[c + 2], bv.z, acc);
        acc = fmaf(wihr[c + 3], bv.w, acc);
      }
      A_[e] = acc;
    }
#pragma unroll
    for (int e = 0; e < E_; ++e) {
      float bk[KC_];
#pragma unroll
      for (int k = 0; k < KC_; ++k) bk[k] = 0.f;
#pragma unroll 4
      for (int c = 0; c < 32; ++c) {
        const float4 s0 = *(const float4*)&swd[(e * OUT_ + c) * KC_ + 0];
        const float4 s1 = *(const float4*)&swd[(e * OUT_ + c) * KC_ + 4];
        const float wc = wihr[c];
        bk[0] = fmaf(wc, s0.x, bk[0]); bk[1] = fmaf(wc, s0.y, bk[1]);
        bk[2] = fmaf(wc, s0.z, bk[2]); bk[3] = fmaf(wc, s0.w, bk[3]);
        bk[4] = fmaf(wc, s1.x, bk[4]); bk[5] = fmaf(wc, s1.y, bk[5]);
        bk[6] = fmaf(wc, s1.z, bk[6]); bk[7] = fmaf(wc, s1.w, bk[7]);
      }
#pragma unroll
      for (int q = 0; q < 4; ++q) Beh[e][q] = packh2(bk[2 * q], bk[2 * q + 1]);
    }
  }

  float h = 0.0f;                       // wave 0, lane ln holds h[ln] in f32

  for (int ic = 0; ic <= NCHB; ++ic) {
    // ---------- producers: chunk ic -> xqrz/xqn[ic&1] ----------
    if (w >= 1 && ic < NCHB) {
      const int p = ic & 1;
      {
        const float x = d[db + tstart + ic * CH_ + ln];
        float silu, gate[E_], bs[KC_];
        kan_scalars(x, gwrd, gbrd, silu, gate, bs);
        float* prow = &packsw[p3][ln][0];
        *(float4*)&prow[0] = *(float4*)&gate[0];
        *(float4*)&prow[4] = *(float4*)&gate[4];
        prow[8] = silu;
        half2_t* bsp = (half2_t*)&prow[10];
#pragma unroll
        for (int q = 0; q < 4; ++q) bsp[q] = packh2(bs[2 * q], bs[2 * q + 1]);
      }
      asm volatile("" ::: "memory");   // order pack-write before t-loop reads (intra-wave)
#pragma unroll 2
      for (int t = 0; t < CH_; ++t) {
        const float* pr = &packsw[p3][t][0];
        const float4 g0 = *(const float4*)&pr[0];
        const float4 g1 = *(const float4*)&pr[4];
        const float silu_t = pr[8];
        const half2_t* bsp = (const half2_t*)&pr[10];
        const half2_t b0 = bsp[0], b1 = bsp[1], b2 = bsp[2], b3 = bsp[3];
        float acc = bihr;
        {
          float in0 = silu_t * A_[0];
          in0 = fdot2_(b0, Beh[0][0], in0); in0 = fdot2_(b1, Beh[0][1], in0);
          in0 = fdot2_(b2, Beh[0][2], in0); in0 = fdot2_(b3, Beh[0][3], in0);
          acc = fmaf(g0.x, in0, acc);
          float in1 = silu_t * A_[1];
          in1 = fdot2_(b0, Beh[1][0], in1); in1 = fdot2_(b1, Beh[1][1], in1);
          in1 = fdot2_(b2, Beh[1][2], in1); in1 = fdot2_(b3, Beh[1][3], in1);
          acc = fmaf(g0.y, in1, acc);
          float in2 = silu_t * A_[2];
          in2 = fdot2_(b0, Beh[2][0], in2); in2 = fdot2_(b1, Beh[2][1], in2);
          in2 = fdot2_(b2, Beh[2][2], in2); in2 = fdot2_(b3, Beh[2][3], in2);
          acc = fmaf(g0.z, in2, acc);
          float in3 = silu_t * A_[3];
          in3 = fdot2_(b0, Beh[3][0], in3); in3 = fdot2_(b1, Beh[3][1], in3);
          in3 = fdot2_(b2, Beh[3][2], in3); in3 = fdot2_(b3, Beh[3][3], in3);
          acc = fmaf(g0.w, in3, acc);
          float in4 = silu_t * A_[4];
          in4 = fdot2_(b0, Beh[4][0], in4); in4 = fdot2_(b1, Beh[4][1], in4);
          in4 = fdot2_(b2, Beh[4][2], in4); in4 = fdot2_(b3, Beh[4][3], in4);
          acc = fmaf(g1.x, in4, acc);
          float in5 = silu_t * A_[5];
          in5 = fdot2_(b0, Beh[5][0], in5); in5 = fdot2_(b1, Beh[5][1], in5);
          in5 = fdot2_(b2, Beh[5][2], in5); in5 = fdot2_(b3, Beh[5][3], in5);
          acc = fmaf(g1.y, in5, acc);
          float in6 = silu_t * A_[6];
          in6 = fdot2_(b0, Beh[6][0], in6); in6 = fdot2_(b1, Beh[6][1], in6);
          in6 = fdot2_(b2, Beh[6][2], in6); in6 = fdot2_(b3, Beh[6][3], in6);
          acc = fmaf(g1.z, in6, acc);
          float in7 = silu_t * A_[7];
          in7 = fdot2_(b0, Beh[7][0], in7); in7 = fdot2_(b1, Beh[7][1], in7);
          in7 = fdot2_(b2, Beh[7][2], in7); in7 = fdot2_(b3, Beh[7][3], in7);
          acc = fmaf(g1.w, in7, acc);
        }
        if (p3 == 0)      ((_Float16*)&xqrz[p][t][ln])[0] = (_Float16)acc;
        else if (p3 == 1) ((_Float16*)&xqrz[p][t][ln])[1] = (_Float16)acc;
        else              xqn[p][t][ln] = (_Float16)acc;
      }
    }

    // ---------- consumer: chunk ic-1 ----------
    if (w == 0 && ic >= 1) {
      const int jc = ic - 1;
      const int p = jc & 1;
      const int tb = tstart + jc * CH_;
      const bool do_store = (jc >= wup);
      half2_t rz0 = u2h2(xqrz[p][0][ln]);
      float xr = (float)rz0.x, xz = (float)rz0.y;
      float xn = (float)xqn[p][0][ln];
      __builtin_amdgcn_s_setprio(1);
#pragma unroll 1
      for (int s = 0; s < CH_; ++s) {
        float ar0 = bhh3[0], ar1 = xr, ar2 = 0.f, ar3 = 0.f;
        float az0 = bhh3[1], az1 = xz, az2 = 0.f, az3 = 0.f;
        float an0 = bhh3[2], an1 = 0.f, an2 = 0.f, an3 = 0.f;
        {
          const half2_t q0 = u2h2(u0.x), q1 = u2h2(u0.y), q2 = u2h2(u0.z), q3 = u2h2(u0.w);
          ar0 = fdot2_(whhp[0][0], q0, ar0); ar1 = fdot2_(whhp[0][1], q1, ar1);
          ar2 = fdot2_(whhp[0][2], q2, ar2); ar3 = fdot2_(whhp[0][3], q3, ar3);
          az0 = fdot2_(whhp[1][0], q0, az0); az1 = fdot2_(whhp[1][1], q1, az1);
          az2 = fdot2_(whhp[1][2], q2, az2); az3 = fdot2_(whhp[1][3], q3, az3);
          an0 = fdot2_(whhp[2][0], q0, an0); an1 = fdot2_(whhp[2][1], q1, an1);
          an2 = fdot2_(whhp[2][2], q2, an2); an3 = fdot2_(whhp[2][3], q3, an3);
        }
        {
          const half2_t q0 = u2h2(u1.x), q1 = u2h2(u1.y), q2 = u2h2(u1.z), q3 = u2h2(u1.w);
          ar0 = fdot2_(whhp[0][4], q0, ar0); ar1 = fdot2_(whhp[0][5], q1, ar1);
          ar2 = fdot2_(whhp[0][6], q2, ar2); ar3 = fdot2_(whhp[0][7], q3, ar3);
          az0 = fdot2_(whhp[1][4], q0, az0); az1 = fdot2_(whhp[1][5], q1, az1);
          az2 = fdot2_(whhp[1][6], q2, az2); az3 = fdot2_(whhp[1][7], q3, az3);
          an0 = fdot2_(whhp[2][4], q0, an0); an1 = fdot2_(whhp[2][5], q1, an1);
          an2 = fdot2_(whhp[2][6], q2, an2); an3 = fdot2_(whhp[2][7], q3, an3);
        }
        {
          const half2_t q0 = u2h2(u2.x), q1 = u2h2(u2.y), q2 = u2h2(u2.z), q3 = u2h2(u2.w);
          ar0 = fdot2_(whhp[0][8], q0, ar0); ar1 = fdot2_(whhp[0][9], q1, ar1);
          ar2 = fdot2_(whhp[0][10], q2, ar2); ar3 = fdot2_(whhp[0][11], q3, ar3);
          az0 = fdot2_(whhp[1][8], q0, az0); az1 = fdot2_(whhp[1][9], q1, az1);
          az2 = fdot2_(whhp[1][10], q2, az2); az3 = fdot2_(whhp[1][11], q3, az3);
          an0 = fdot2_(whhp[2][8], q0, an0); an1 = fdot2_(whhp[2][9], q1, an1);
          an2 = fdot2_(whhp[2][10], q2, an2); an3 = fdot2_(whhp[2][11], q3, an3);
        }
        {
          const half2_t q0 = u2h2(u3.x), q1 = u2h2(u3.y), q2 = u2h2(u3.z), q3 = u2h2(u3.w);
          ar0 = fdot2_(whhp[0][12], q0, ar0); ar1 = fdot2_(whhp[0][13], q1, ar1);
          ar2 = fdot2_(whhp[0][14], q2, ar2); ar3 = fdot2_(whhp[0][15], q3, ar3);
          az0 = fdot2_(whhp[1][12], q0, az0); az1 = fdot2_(whhp[1][13], q1, az1);
          az2 = fdot2_(whhp[1][14], q2, az2); az3 = fdot2_(whhp[1][15], q3, az3);
          an0 = fdot2_(whhp[2][12], q0, an0); an1 = fdot2_(whhp[2][13], q1, an1);
          an2 = fdot2_(whhp[2][14], q2, an2); an3 = fdot2_(whhp[2][15], q3, an3);
        }
        {
          const half2_t q0 = u2h2(u4.x), q1 = u2h2(u4.y), q2 = u2h2(u4.z), q3 = u2h2(u4.w);
          ar0 = fdot2_(whhp[0][16], q0, ar0); ar1 = fdot2_(whhp[0][17], q1, ar1);
          ar2 = fdot2_(whhp[0][18], q2, ar2); ar3 = fdot2_(whhp[0][19], q3, ar3);
          az0 = fdot2_(whhp[1][16], q0, az0); az1 = fdot2_(whhp[1][17], q1, az1);
          az2 = fdot2_(whhp[1][18], q2, az2); az3 = fdot2_(whhp[1][19], q3, az3);
          an0 = fdot2_(whhp[2][16], q0, an0); an1 = fdot2_(whhp[2][17], q1, an1);
          an2 = fdot2_(whhp[2][18], q2, an2); an3 = fdot2_(whhp[2][19], q3, an3);
        }
        {
          const half2_t q0 = u2h2(u5.x), q1 = u2h2(u5.y), q2 = u2h2(u5.z), q3 = u2h2(u5.w);
          ar0 = fdot2_(whhp[0][20], q0, ar0); ar1 = fdot2_(whhp[0][21], q1, ar1);
          ar2 = fdot2_(whhp[0][22], q2, ar2); ar3 = fdot2_(whhp[0][23], q3, ar3);
          az0 = fdot2_(whhp[1][20], q0, az0); az1 = fdot2_(whhp[1][21], q1, az1);
          az2 = fdot2_(whhp[1][22], q2, az2); az3 = fdot2_(whhp[1][23], q3, az3);
          an0 = fdot2_(whhp[2][20], q0, an0); an1 = fdot2_(whhp[2][21], q1, an1);
          an2 = fdot2_(whhp[2][22], q2, an2); an3 = fdot2_(whhp[2][23], q3, an3);
        }
        {
          const half2_t q0 = u2h2(u6.x), q1 = u2h2(u6.y), q2 = u2h2(u6.z), q3 = u2h2(u6.w);
          ar0 = fdot2_(whhp[0][24], q0, ar0); ar1 = fdot2_(whhp[0][25], q1, ar1);
          ar2 = fdot2_(whhp[0][26], q2, ar2); ar3 = fdot2_(whhp[0][27], q3, ar3);
          az0 = fdot2_(whhp[1][24], q0, az0); az1 = fdot2_(whhp[1][25], q1, az1);
          az2 = fdot2_(whhp[1][26], q2, az2); az3 = fdot2_(whhp[1][27], q3, az3);
          an0 = fdot2_(whhp[2][24], q0, an0); an1 = fdot2_(whhp[2][25], q1, an1);
          an2 = fdot2_(whhp[2][26], q2, an2); an3 = fdot2_(whhp[2][27], q3, an3);
        }
        {
          const half2_t q0 = u2h2(u7.x), q1 = u2h2(u7.y), q2 = u2h2(u7.z), q3 = u2h2(u7.w);
          ar0 = fdot2_(whhp[0][28], q0, ar0); ar1 = fdot2_(whhp[0][29], q1, ar1);
          ar2 = fdot2_(whhp[0][30], q2, ar2); ar3 = fdot2_(whhp[0][31], q3, ar3);
          az0 = fdot2_(whhp[1][28], q0, az0); az1 = fdot2_(whhp[1][29], q1, az1);
          az2 = fdot2_(whhp[1][30], q2, az2); az3 = fdot2_(whhp[1][31], q3, az3);
          an0 = fdot2_(whhp[2][28], q0, an0); an1 = fdot2_(whhp[2][29], q1, an1);
          an2 = fdot2_(whhp[2][30], q2, an2); an3 = fdot2_(whhp[2][31], q3, an3);
        }
        const float hr = (ar0 + ar1) + (ar2 + ar3);
        const float hz = (az0 + az1) + (az2 + az3);
        const float hn = (an0 + an1) + (an2 + an3);
        const float r = frcp(1.0f + exp2_(hr));
        const float z = frcp(1.0f + exp2_(hz));
        const float tn = frcp(1.0f + exp2_(fmaf(r, hn, xn)));
        const float n = fmaf(2.0f, tn, -1.0f);
        h = n + z * (h - n);
        hbc[ln] = __builtin_bit_cast(unsigned short, (_Float16)h);
        asm volatile("" ::: "memory");   // write before aliased reads
        const int sn = (s + 1) & (CH_ - 1);
        const unsigned rzn = xqrz[p][sn][ln];
        const _Float16 xnn = xqn[p][sn][ln];
        u0 = hq4[0]; u1 = hq4[1]; u2 = hq4[2]; u3 = hq4[3];
        u4 = hq4[4]; u5 = hq4[5]; u6 = hq4[6]; u7 = hq4[7];
        asm volatile("" ::: "memory");   // pin read issue before the tail
        if (do_store) outrow[(size_t)(tb + s) * 96 + ln] = h;
        const half2_t rzh = u2h2(rzn);
        xr = (float)rzh.x; xz = (float)rzh.y; xn = (float)xnn;
      }
      __builtin_amdgcn_s_setprio(0);
    }
    __syncthreads();   // one uniform barrier per chunk iteration
  }

  // ======================= Conv tail: 8 tiles of (row b, half seg) =======================
  {
    auto fa  = (float (*)[136])smem_;                      // 17408 B
    auto cwl = (float (*)[161])(smem_ + 17408);            // 20608 B
    auto swl = (float (*)[OUT_][KC_])(smem_ + 38016);      //  8192 B
    auto bwl = (float (*)[OUT_])(smem_ + 46208);           //  1024 B
    float* gwl = (float*)(smem_ + 47232);
    float* gbl = (float*)(smem_ + 47264);

    for (int i = tid; i < OUT_ * OUT_ * 5; i += 256) cwl[i / 160][i % 160] = cw[i];
    for (int i = tid; i < E_ * OUT_ * KC_; i += 256) ((float*)swl)[i] = swa[i];
    for (int i = tid; i < E_ * OUT_; i += 256) ((float*)bwl)[i] = bwa[i];
    if (tid < E_) { gwl[tid] = gwa[tid]; gbl[tid] = gba[tid]; }
    __syncthreads();

#pragma unroll 1
    for (int it = 0; it < 8; ++it) {
      const int t0 = (seg * 8 + it) * TILE_A;
      if (tid < TILE_A + 4) {
        const int i = tid;
        const int t = t0 + i - 2;
        const bool inr = (t >= 0) && (t < T_);
        const float x = inr ? a[db + t] : 0.0f;
        float gwr[E_], gbr[E_];
#pragma unroll
        for (int e = 0; e < E_; ++e) { gwr[e] = gwl[e]; gbr[e] = gbl[e]; }
        float silu, gate[E_], bs[KC_];
        kan_scalars(x, gwr, gbr, silu, gate, bs);
#pragma unroll 4
        for (int cc = 0; cc < OUT_; ++cc) {
          float accb = 0.f, accs = 0.f;
#pragma unroll
          for (int e = 0; e < E_; ++e) {
            accb = fmaf(gate[e], bwl[e][cc], accb);
            const float4 s0 = *(const float4*)&swl[e][cc][0];
            const float4 s1 = *(const float4*)&swl[e][cc][4];
            float dot = bs[0]*s0.x + bs[1]*s0.y + bs[2]*s0.z + bs[3]*s0.w
                      + bs[4]*s1.x + bs[5]*s1.y + bs[6]*s1.z + bs[7]*s1.w;
            accs = fmaf(gate[e], dot, accs);
          }
          fa[cc][i] = inr ? fmaf(silu, accb, accs) : 0.0f;
        }
      }
      __syncthreads();
      {
        const int o = tid & 31;
        const int grp = tid >> 5;
        const float bias = cb[o];
        float acc[16];
#pragma unroll
        for (int q = 0; q < 16; ++q) acc[q] = bias;
        for (int c = 0; c < OUT_; ++c) {
          float col[20];
#pragma unroll
          for (int q = 0; q < 5; ++q)
            *(float4*)&col[q * 4] = *(const float4*)&fa[c][grp * 16 + q * 4];
#pragma unroll
          for (int jj = 0; jj < 5; ++jj) {
            const float wv = cwl[o][c * 5 + jj];
#pragma unroll
            for (int q = 0; q < 16; ++q) acc[q] = fmaf(col[q + jj], wv, acc[q]);
          }
        }
#pragma unroll
        for (int q = 0; q < 16; ++q) {
          const int t = t0 + grp * 16 + q;
          out[(db + t) * 96 + o] = fmaxf(acc[q], 0.0f);
        }
      }
      __syncthreads();
    }
  }
}

extern "C" void kernel_launch(void* const* d_in, const int* in_sizes, int n_in,
                              void* d_out, int out_size, void* d_ws, size_t ws_size,
                              hipStream_t stream) {
  (void)in_sizes; (void)n_in; (void)out_size; (void)d_ws; (void)ws_size;
  const float* a        = (const float*)d_in[0];
  const float* d        = (const float*)d_in[1];
  const float* gate_w_a = (const float*)d_in[2];
  const float* gate_b_a = (const float*)d_in[3];
  const float* base_w_a = (const float*)d_in[4];
  const float* spln_w_a = (const float*)d_in[5];
  const float* gate_w_d = (const float*)d_in[6];
  const float* gate_b_d = (const float*)d_in[7];
  const float* base_w_d = (const float*)d_in[8];
  const float* spln_w_d = (const float*)d_in[9];
  const float* conv_w   = (const float*)d_in[10];
  const float* conv_b   = (const float*)d_in[11];
  const float* w_ih     = (const float*)d_in[12];
  const float* w_hh     = (const float*)d_in[13];
  const float* b_ih     = (const float*)d_in[14];
  const float* b_hh     = (const float*)d_in[15];
  float* out = (float*)d_out;

  fused5_kernel<<<NSEG * B_, 256, 0, stream>>>(
      a, d, gate_w_a, gate_b_a, base_w_a, spln_w_a,
      gate_w_d, gate_b_d, base_w_d, spln_w_d,
      conv_w, conv_b, w_ih, w_hh, b_ih, b_hh, out);
}